// Round 1
// baseline (39949.814 us; speedup 1.0000x reference)
//
#include <hip/hip_runtime.h>
#include <stdint.h>

#define BB 512
#define T_HIST 256
#define FUTN 32
#define T_TOT 288
#define D_IN 64
#define HH 512
#define KSTR 512
#define SZ_HB (512*512)   // elems per parity buffer for h/z

typedef float f32x4 __attribute__((ext_vector_type(4)));
typedef __bf16 bf16x8 __attribute__((ext_vector_type(8)));

__device__ __forceinline__ unsigned short f2bf_rne(float x){
    union { float f; uint32_t u; } v; v.f = x;
    uint32_t r = v.u + 0x7FFFu + ((v.u >> 16) & 1u);
    return (unsigned short)(r >> 16);
}
__device__ __forceinline__ float bf2f(unsigned short b){
    union { uint32_t u; float f; } v; v.u = ((uint32_t)b) << 16;
    return v.f;
}
__device__ __forceinline__ float sigm(float x){ return 1.0f/(1.0f + __expf(-x)); }
__device__ __forceinline__ float tanh_fast(float x){ return 2.0f/(1.0f + __expf(-2.0f*x)) - 1.0f; }

// ---------------------------------------------------------------------------
// Fused gates GEMM + LSTM cell update.
// WG: 512 threads = 8 waves = (2 M-halves) x (4 gates). Tile: 64 M x 32 h x 4 gates.
// gates = A1 @ B1^T + A2 @ B2^T + bias, with 3-term bf16 split (hi*hi+lo*hi+hi*lo).
// Grid for one call: 128 WGs (8 M-tiles x 16 h-tiles).
// ---------------------------------------------------------------------------
__device__ void dev_gates(int wg, int tid,
    const unsigned short* A1h, const unsigned short* A1l,
    const unsigned short* A2h, const unsigned short* A2l,
    const unsigned short* B1h, const unsigned short* B1l,
    const unsigned short* B2h, const unsigned short* B2l,
    const float* bias, float* Cst, unsigned short* Hh, unsigned short* Hl,
    unsigned char* smem)
{
    const int m0  = (wg & 7) * 64;
    const int hu0 = (wg >> 3) * 32;
    const int w = tid >> 6, lane = tid & 63;
    const int g = w & 3, mh = w >> 2;

    f32x4 acc[2][2];
#pragma unroll
    for (int a = 0; a < 2; a++)
#pragma unroll
        for (int b = 0; b < 2; b++) { f32x4 z = {0.f,0.f,0.f,0.f}; acc[a][b] = z; }

    int dstoff[6];
#pragma unroll
    for (int i = 0; i < 6; i++) {
        int v = tid + i*512;
        dstoff[i] = (v >> 3)*144 + (v & 7)*16;
    }

    for (int pass = 0; pass < 2; pass++) {
        const unsigned short* Ah = pass ? A2h : A1h;
        const unsigned short* Al = pass ? A2l : A1l;
        const unsigned short* Bh = pass ? B2h : B1h;
        const unsigned short* Bl = pass ? B2l : B1l;
        const unsigned short* rowp[6];
#pragma unroll
        for (int i = 0; i < 6; i++) {
            int v = tid + i*512;
            int r = v >> 3, c = v & 7;
            const unsigned short* p;
            if (r < 128) {
                int rr = r & 63;
                p = (r < 64 ? Ah : Al) + (size_t)(m0 + rr)*KSTR;
            } else {
                int br = (r - 128) & 127;
                int grow = ((br >> 5) << 9) + hu0 + (br & 31);
                p = (r < 256 ? Bh : Bl) + (size_t)grow*KSTR;
            }
            rowp[i] = p + c*8;
        }
        uint4 ld[6];
#pragma unroll
        for (int i = 0; i < 6; i++) ld[i] = *(const uint4*)(rowp[i]);

        for (int kc = 0; kc < 8; kc++) {
            __syncthreads();
#pragma unroll
            for (int i = 0; i < 6; i++) *(uint4*)(smem + dstoff[i]) = ld[i];
            __syncthreads();
            if (kc < 7) {
#pragma unroll
                for (int i = 0; i < 6; i++) ld[i] = *(const uint4*)(rowp[i] + (kc+1)*64);
            }
#pragma unroll
            for (int ks = 0; ks < 2; ks++) {
                const int fo = ks*64 + (lane >> 4)*16;
                bf16x8 ah[2], al[2], bh[2], bl[2];
#pragma unroll
                for (int fm = 0; fm < 2; fm++) {
                    int row = mh*32 + fm*16 + (lane & 15);
                    ah[fm] = *(const bf16x8*)(smem + row*144 + fo);
                    al[fm] = *(const bf16x8*)(smem + (64 + row)*144 + fo);
                }
#pragma unroll
                for (int fn = 0; fn < 2; fn++) {
                    int br = g*32 + fn*16 + (lane & 15);
                    bh[fn] = *(const bf16x8*)(smem + (128 + br)*144 + fo);
                    bl[fn] = *(const bf16x8*)(smem + (256 + br)*144 + fo);
                }
#pragma unroll
                for (int fm = 0; fm < 2; fm++)
#pragma unroll
                    for (int fn = 0; fn < 2; fn++) {
                        acc[fm][fn] = __builtin_amdgcn_mfma_f32_16x16x32_bf16(ah[fm], bh[fn], acc[fm][fn], 0,0,0);
                        acc[fm][fn] = __builtin_amdgcn_mfma_f32_16x16x32_bf16(al[fm], bh[fn], acc[fm][fn], 0,0,0);
                        acc[fm][fn] = __builtin_amdgcn_mfma_f32_16x16x32_bf16(ah[fm], bl[fn], acc[fm][fn], 0,0,0);
                    }
            }
        }
    }

    // ---- epilogue: gate exchange through LDS + cell update ----
    __syncthreads();
    float* gbuf = (float*)smem;  // [4][64][36]
#pragma unroll
    for (int fm = 0; fm < 2; fm++)
#pragma unroll
        for (int fn = 0; fn < 2; fn++) {
            int row = mh*32 + fm*16 + (lane >> 4)*4;
            int col = fn*16 + (lane & 15);
#pragma unroll
            for (int j = 0; j < 4; j++)
                gbuf[(g*64 + row + j)*36 + col] = acc[fm][fn][j];
        }
    __syncthreads();
#pragma unroll
    for (int ii = 0; ii < 4; ii++) {
        int cell = tid + ii*512;          // 2048 cells: 64 m x 32 h
        int ml = cell >> 5, hl = cell & 31;
        int hu = hu0 + hl;
        float gi = gbuf[(0*64 + ml)*36 + hl] + bias[hu];
        float gf = gbuf[(1*64 + ml)*36 + hl] + bias[512 + hu];
        float gg = gbuf[(2*64 + ml)*36 + hl] + bias[1024 + hu];
        float go = gbuf[(3*64 + ml)*36 + hl] + bias[1536 + hu];
        int gidx = (m0 + ml)*HH + hu;
        float c_old = Cst[gidx];
        float cn = sigm(gf)*c_old + sigm(gi)*tanh_fast(gg);
        float hn = sigm(go)*tanh_fast(cn);
        Cst[gidx] = cn;
        unsigned short hb = f2bf_rne(hn);
        Hh[gidx] = hb;
        Hl[gidx] = f2bf_rne(hn - bf2f(hb));
    }
}

// ---- z = x_row @ W_in^T + b_in, split to bf16 hi/lo. 64 WGs x 512 thr, 8 rows/WG.
__device__ void dev_zproj(int wg, int tid, const float* x_src, int row_stride, int col_off,
    const float* W_in, const float* b_in,
    unsigned short* zh, unsigned short* zl, unsigned char* smem)
{
    float* xs = (float*)smem;  // [8][64]
    int m0 = wg * 8;
    {
        int r = tid >> 6, d = tid & 63;
        xs[r*64 + d] = x_src[(size_t)(m0 + r)*row_stride + col_off + d];
    }
    __syncthreads();
    int n = tid;
    float a[8];
#pragma unroll
    for (int r = 0; r < 8; r++) a[r] = b_in[n];
    for (int d4 = 0; d4 < 16; d4++) {
        float4 w4 = *(const float4*)(W_in + n*64 + d4*4);
#pragma unroll
        for (int r = 0; r < 8; r++) {
            const float* xr = xs + r*64 + d4*4;
            a[r] += xr[0]*w4.x + xr[1]*w4.y + xr[2]*w4.z + xr[3]*w4.w;
        }
    }
#pragma unroll
    for (int r = 0; r < 8; r++) {
        unsigned short hb = f2bf_rne(a[r]);
        zh[(m0 + r)*HH + n] = hb;
        zl[(m0 + r)*HH + n] = f2bf_rne(a[r] - bf2f(hb));
    }
}

// ---- out[:, tt, :] = h1 @ W_out^T + b_out. 32 WGs x 512 thr, 16 rows/WG.
__device__ void dev_outproj(int wg, int tid, const unsigned short* hh, const unsigned short* hl,
    const float* W_out, const float* b_out, float* out, int tt, unsigned char* smem)
{
    float* hs = (float*)smem;  // [16][512]
    int m0 = wg * 16;
#pragma unroll
    for (int i = 0; i < 16; i++) {
        int idx = tid + i*512;
        int r = idx >> 9, k = idx & 511;
        int gidx = (m0 + r)*HH + k;
        hs[idx] = bf2f(hh[gidx]) + bf2f(hl[gidx]);
    }
    __syncthreads();
#pragma unroll
    for (int o = 0; o < 2; o++) {
        int idx = tid + o*512;
        int r = idx >> 6, d = idx & 63;
        float acc = b_out[d];
        const float* wr = W_out + d*512;
        for (int k4 = 0; k4 < 128; k4++) {
            float4 w4 = *(const float4*)(wr + k4*4);
            const float* hr = hs + r*512 + k4*4;
            acc += hr[0]*w4.x + hr[1]*w4.y + hr[2]*w4.z + hr[3]*w4.w;
        }
        out[(size_t)(m0 + r)*T_TOT*D_IN + tt*D_IN + d] = acc;
    }
}

// ---------------------------------------------------------------------------
// One pipelined history step: gates0(t) || gates1(t-1) || zproj(t+1) || outproj(t-2)
// ---------------------------------------------------------------------------
__global__ __launch_bounds__(512)
void hist_step(int t, const float* x_hist, const float* W_in, const float* b_in,
    const unsigned short* Whi, const unsigned short* Wlo, const float* b01,
    unsigned short* zhi, unsigned short* zlo,
    unsigned short* h0hi, unsigned short* h0lo,
    unsigned short* h1hi, unsigned short* h1lo,
    float* c0, float* c1,
    const float* W_out, const float* b_out, float* out)
{
    __shared__ unsigned char smem[55296];
    int bid = blockIdx.x, tid = threadIdx.x;
    if (bid < 128) {
        if (t < 256) {
            int p = t & 1, pm = (t - 1) & 1;
            dev_gates(bid, tid,
                zhi + p*SZ_HB, zlo + p*SZ_HB,
                h0hi + pm*SZ_HB, h0lo + pm*SZ_HB,
                Whi + (0 << 20), Wlo + (0 << 20),
                Whi + (2 << 20), Wlo + (2 << 20),
                b01, c0, h0hi + p*SZ_HB, h0lo + p*SZ_HB, smem);
        }
    } else if (bid < 256) {
        int s = t - 1;
        if (s >= 0) {
            int p = s & 1, pm = (s - 1) & 1;
            dev_gates(bid - 128, tid,
                h0hi + p*SZ_HB, h0lo + p*SZ_HB,
                h1hi + pm*SZ_HB, h1lo + pm*SZ_HB,
                Whi + (1 << 20), Wlo + (1 << 20),
                Whi + (3 << 20), Wlo + (3 << 20),
                b01 + 2048, c1, h1hi + p*SZ_HB, h1lo + p*SZ_HB, smem);
        }
    } else if (bid < 320) {
        int tt = t + 1;
        if (tt < 256)
            dev_zproj(bid - 256, tid, x_hist, T_HIST*D_IN, tt*D_IN, W_in, b_in,
                      zhi + (tt & 1)*SZ_HB, zlo + (tt & 1)*SZ_HB, smem);
    } else {
        int s = t - 2;
        if (s >= 0)
            dev_outproj(bid - 320, tid, h1hi + (s & 1)*SZ_HB, h1lo + (s & 1)*SZ_HB,
                        W_out, b_out, out, s, smem);
    }
}

__global__ __launch_bounds__(512)
void gates_standalone(const unsigned short* A1h, const unsigned short* A1l,
    const unsigned short* A2h, const unsigned short* A2l,
    const unsigned short* B1h, const unsigned short* B1l,
    const unsigned short* B2h, const unsigned short* B2l,
    const float* bias, float* Cst, unsigned short* Hh, unsigned short* Hl)
{
    __shared__ unsigned char smem[55296];
    dev_gates(blockIdx.x, threadIdx.x, A1h, A1l, A2h, A2l, B1h, B1l, B2h, B2l,
              bias, Cst, Hh, Hl, smem);
}

__global__ __launch_bounds__(512)
void zproj_standalone(const float* x_hist, const float* W_in, const float* b_in,
                      unsigned short* zh, unsigned short* zl)
{
    __shared__ unsigned char smem[2048];
    dev_zproj(blockIdx.x, threadIdx.x, x_hist, T_HIST*D_IN, 0, W_in, b_in, zh, zl, smem);
}

// ---- future bridge: out(t-1) -> d_out and z(t) = out @ W_in^T + b_in ----
__global__ __launch_bounds__(512)
void fut_bridge(int t, const unsigned short* h1hi_all, const unsigned short* h1lo_all,
                const float* W_out, const float* b_out,
                const float* W_in, const float* b_in,
                float* out, unsigned short* zh_all, unsigned short* zl_all)
{
    __shared__ float hs[16*512];
    __shared__ float outs[16*68];
    int wg = blockIdx.x, tid = threadIdx.x;
    int m0 = wg * 16;
    int sp = (t - 1) & 1;
    const unsigned short* hh = h1hi_all + sp*SZ_HB;
    const unsigned short* hl = h1lo_all + sp*SZ_HB;
#pragma unroll
    for (int i = 0; i < 16; i++) {
        int idx = tid + i*512;
        int r = idx >> 9, k = idx & 511;
        int gidx = (m0 + r)*HH + k;
        hs[idx] = bf2f(hh[gidx]) + bf2f(hl[gidx]);
    }
    __syncthreads();
#pragma unroll
    for (int o = 0; o < 2; o++) {
        int idx = tid + o*512;
        int r = idx >> 6, d = idx & 63;
        float acc = b_out[d];
        const float* wr = W_out + d*512;
        for (int k4 = 0; k4 < 128; k4++) {
            float4 w4 = *(const float4*)(wr + k4*4);
            const float* hr = hs + r*512 + k4*4;
            acc += hr[0]*w4.x + hr[1]*w4.y + hr[2]*w4.z + hr[3]*w4.w;
        }
        outs[r*68 + d] = acc;
        out[(size_t)(m0 + r)*T_TOT*D_IN + (t - 1)*D_IN + d] = acc;
    }
    __syncthreads();
    int n = tid;
    int zp = t & 1;
    unsigned short* zh = zh_all + zp*SZ_HB;
    unsigned short* zl = zl_all + zp*SZ_HB;
    float a[16];
#pragma unroll
    for (int r = 0; r < 16; r++) a[r] = b_in[n];
    for (int d4 = 0; d4 < 16; d4++) {
        float4 w4 = *(const float4*)(W_in + n*64 + d4*4);
#pragma unroll
        for (int r = 0; r < 16; r++) {
            const float* orow = outs + r*68 + d4*4;
            a[r] += orow[0]*w4.x + orow[1]*w4.y + orow[2]*w4.z + orow[3]*w4.w;
        }
    }
#pragma unroll
    for (int r = 0; r < 16; r++) {
        unsigned short hb = f2bf_rne(a[r]);
        zh[(m0 + r)*HH + n] = hb;
        zl[(m0 + r)*HH + n] = f2bf_rne(a[r] - bf2f(hb));
    }
}

// ---- prep: split the 4 big weight matrices into bf16 hi/lo, combine biases ----
__global__ void split_weights(const float* Wih, const float* Whh,
                              unsigned short* Whi, unsigned short* Wlo)
{
    int idx = (blockIdx.x*256 + threadIdx.x)*4;   // 4 * 2^20 elems total
    int m = idx >> 20;
    int off = idx & ((1 << 20) - 1);
    const float* src = (m < 2 ? Wih : Whh) + ((size_t)(m & 1) << 20) + off;
    float4 v = *(const float4*)(src);
    float vv[4] = {v.x, v.y, v.z, v.w};
#pragma unroll
    for (int j = 0; j < 4; j++) {
        unsigned short hb = f2bf_rne(vv[j]);
        Whi[idx + j] = hb;
        Wlo[idx + j] = f2bf_rne(vv[j] - bf2f(hb));
    }
}

__global__ void prep_bias(const float* bih, const float* bhh, float* b01)
{
    int i = blockIdx.x*256 + threadIdx.x;
    if (i < 4096) b01[i] = bih[i] + bhh[i];
}

// ---------------------------------------------------------------------------
extern "C" void kernel_launch(void* const* d_in, const int* in_sizes, int n_in,
                              void* d_out, int out_size, void* d_ws, size_t ws_size,
                              hipStream_t stream)
{
    (void)in_sizes; (void)n_in; (void)out_size; (void)ws_size;
    const float* x_hist = (const float*)d_in[0];
    const float* W_in   = (const float*)d_in[1];
    const float* b_in   = (const float*)d_in[2];
    const float* W_ih   = (const float*)d_in[3];
    const float* W_hh   = (const float*)d_in[4];
    const float* b_ih   = (const float*)d_in[5];
    const float* b_hh   = (const float*)d_in[6];
    const float* W_out  = (const float*)d_in[7];
    const float* b_out  = (const float*)d_in[8];
    float* out = (float*)d_out;

    uint8_t* ws = (uint8_t*)d_ws;
    size_t off = 0;
    auto alloc = [&](size_t bytes) -> void* {
        void* p = ws + off; off += (bytes + 255) & ~(size_t)255; return p;
    };
    unsigned short* Whi = (unsigned short*)alloc((size_t)4*(1 << 20)*2);
    unsigned short* Wlo = (unsigned short*)alloc((size_t)4*(1 << 20)*2);
    float*          b01 = (float*)alloc(4096*4);
    uint8_t* state_base = ws + off;
    unsigned short* zhi  = (unsigned short*)alloc((size_t)2*SZ_HB*2);
    unsigned short* zlo  = (unsigned short*)alloc((size_t)2*SZ_HB*2);
    unsigned short* h0hi = (unsigned short*)alloc((size_t)2*SZ_HB*2);
    unsigned short* h0lo = (unsigned short*)alloc((size_t)2*SZ_HB*2);
    unsigned short* h1hi = (unsigned short*)alloc((size_t)2*SZ_HB*2);
    unsigned short* h1lo = (unsigned short*)alloc((size_t)2*SZ_HB*2);
    float* c0 = (float*)alloc((size_t)SZ_HB*4);
    float* c1 = (float*)alloc((size_t)SZ_HB*4);
    size_t state_bytes = (size_t)((ws + off) - state_base);

    hipMemsetAsync(state_base, 0, state_bytes, stream);
    split_weights<<<4096, 256, 0, stream>>>(W_ih, W_hh, Whi, Wlo);
    prep_bias<<<16, 256, 0, stream>>>(b_ih, b_hh, b01);
    zproj_standalone<<<64, 512, 0, stream>>>(x_hist, W_in, b_in, zhi, zlo); // z(0) -> parity 0

    for (int t = 0; t <= 256; t++)
        hist_step<<<352, 512, 0, stream>>>(t, x_hist, W_in, b_in, Whi, Wlo, b01,
            zhi, zlo, h0hi, h0lo, h1hi, h1lo, c0, c1, W_out, b_out, out);

    for (int ft = 0; ft < FUTN; ft++) {
        int t = 256 + ft;
        fut_bridge<<<32, 512, 0, stream>>>(t, h1hi, h1lo, W_out, b_out, W_in, b_in,
                                           out, zhi, zlo);
        int p = t & 1, pm = (t - 1) & 1;
        gates_standalone<<<128, 512, 0, stream>>>(
            zhi + p*SZ_HB, zlo + p*SZ_HB, h0hi + pm*SZ_HB, h0lo + pm*SZ_HB,
            Whi + (0 << 20), Wlo + (0 << 20), Whi + (2 << 20), Wlo + (2 << 20),
            b01, c0, h0hi + p*SZ_HB, h0lo + p*SZ_HB);
        gates_standalone<<<128, 512, 0, stream>>>(
            h0hi + p*SZ_HB, h0lo + p*SZ_HB, h1hi + pm*SZ_HB, h1lo + pm*SZ_HB,
            Whi + (1 << 20), Wlo + (1 << 20), Whi + (3 << 20), Wlo + (3 << 20),
            b01 + 2048, c1, h1hi + p*SZ_HB, h1lo + p*SZ_HB);
    }
    // final output column 287 from h1(287)
    fut_bridge<<<32, 512, 0, stream>>>(288, h1hi, h1lo, W_out, b_out, W_in, b_in,
                                       out, zhi, zlo);
}

// Round 2
// 37255.191 us; speedup vs baseline: 1.0723x; 1.0723x over previous
//
#include <hip/hip_runtime.h>
#include <stdint.h>

#define FUTN 32
#define T_TOT 288
#define HH 512
#define SZ_HB (512*512)
#define LDS_A_OFF 131072
#define LDS_TOTAL 163840

typedef float f32x4 __attribute__((ext_vector_type(4)));
typedef __bf16 bf16x8 __attribute__((ext_vector_type(8)));

__device__ __forceinline__ unsigned short f2bf_rne(float x){
    union { float f; uint32_t u; } v; v.f = x;
    uint32_t r = v.u + 0x7FFFu + ((v.u >> 16) & 1u);
    return (unsigned short)(r >> 16);
}
__device__ __forceinline__ float bf2f(unsigned short b){
    union { uint32_t u; float f; } v; v.u = ((uint32_t)b) << 16;
    return v.f;
}
__device__ __forceinline__ float sigm(float x){ return 1.0f/(1.0f + __expf(-x)); }
__device__ __forceinline__ float tanh_fast(float x){ return 2.0f/(1.0f + __expf(-2.0f*x)) - 1.0f; }

// ---- grid-wide sync: agent-scope atomics (per guide §6 G16) ----
__device__ __forceinline__ void gsync(int tid, unsigned* cnt, unsigned* gen) {
    __syncthreads();
    if (tid == 0) {
        unsigned g = __hip_atomic_load(gen, __ATOMIC_RELAXED, __HIP_MEMORY_SCOPE_AGENT);
        unsigned old = __hip_atomic_fetch_add(cnt, 1u, __ATOMIC_ACQ_REL, __HIP_MEMORY_SCOPE_AGENT);
        if (old == 255u) {
            __hip_atomic_store(cnt, 0u, __ATOMIC_RELAXED, __HIP_MEMORY_SCOPE_AGENT);
            __hip_atomic_fetch_add(gen, 1u, __ATOMIC_RELEASE, __HIP_MEMORY_SCOPE_AGENT);
        } else {
            while (__hip_atomic_load(gen, __ATOMIC_RELAXED, __HIP_MEMORY_SCOPE_AGENT) == g)
                __builtin_amdgcn_s_sleep(4);
            (void)__hip_atomic_load(gen, __ATOMIC_ACQUIRE, __HIP_MEMORY_SCOPE_AGENT);
        }
    }
    __syncthreads();
}

// ---------------------------------------------------------------------------
// Gates for one layer-step. WG owns 32 gate-rows (4 gates x 8 hu) x 256 batch
// rows. B (weights, hi+lo, ih+hh) resident in LDS[0..128KB) swizzled.
// A staged per K=32 chunk into LDS[128KB..160KB) with reg prefetch.
// c kept in registers across the whole sequence.
// ---------------------------------------------------------------------------
__device__ __forceinline__ void do_gates(int tid, int m0, int slice,
    const unsigned short* A1h, const unsigned short* A1l,
    const unsigned short* A2h, const unsigned short* A2l,
    float bI, float bF, float bG, float bO,
    float* c_reg, unsigned short* Hh, unsigned short* Hl,
    unsigned char* smem)
{
    const int lane = tid & 63, w = tid >> 6;
    unsigned char* Ab = smem + LDS_A_OFF;

    const int s7 = tid & 7;
    const bool isLo = s7 >= 4;
    const int soff = (s7 & 3) * 8;
    int rI[4], dstoff[4];
#pragma unroll
    for (int i = 0; i < 4; i++) {
        rI[i] = i*64 + (tid >> 3);
        dstoff[i] = rI[i]*128 + ((s7 ^ (rI[i] & 7)) << 4);
    }

    f32x4 acc[2][2];
#pragma unroll
    for (int a = 0; a < 2; a++)
#pragma unroll
        for (int b = 0; b < 2; b++) { f32x4 z = {0.f,0.f,0.f,0.f}; acc[a][b] = z; }

    uint4 ld[4];
    {
        const unsigned short* S = isLo ? A1l : A1h;
#pragma unroll
        for (int i = 0; i < 4; i++)
            ld[i] = *(const uint4*)(S + (size_t)(m0 + rI[i])*HH + soff);
    }

    for (int kc = 0; kc < 32; kc++) {
        __syncthreads();                       // previous chunk consumed
#pragma unroll
        for (int i = 0; i < 4; i++) *(uint4*)(Ab + dstoff[i]) = ld[i];
        __syncthreads();                       // chunk staged
        if (kc < 31) {
            int kn = kc + 1;
            const unsigned short* S = (kn < 16) ? (isLo ? A1l : A1h) : (isLo ? A2l : A2h);
            int k0 = (kn & 15) * 32;
#pragma unroll
            for (int i = 0; i < 4; i++)
                ld[i] = *(const uint4*)(S + (size_t)(m0 + rI[i])*HH + k0 + soff);
        }
        const int mat = kc >> 4;               // 0: ih, 1: hh
        const int ks  = (kc & 15)*4 + (lane >> 4);
        bf16x8 ah[2], al[2], bh[2], bl[2];
#pragma unroll
        for (int fm = 0; fm < 2; fm++) {
            int row = w*32 + fm*16 + (lane & 15);
            int sh = lane >> 4;
            ah[fm] = *(const bf16x8*)(Ab + row*128 + ((sh ^ (row & 7)) << 4));
            al[fm] = *(const bf16x8*)(Ab + row*128 + (((4 + sh) ^ (row & 7)) << 4));
        }
#pragma unroll
        for (int fn = 0; fn < 2; fn++) {
            int br = fn*16 + (lane & 15);
            int off = br*1024 + ((ks ^ (br & 7)) << 4);
            bh[fn] = *(const bf16x8*)(smem + (mat*2 + 0)*32768 + off);
            bl[fn] = *(const bf16x8*)(smem + (mat*2 + 1)*32768 + off);
        }
#pragma unroll
        for (int fm = 0; fm < 2; fm++)
#pragma unroll
            for (int fn = 0; fn < 2; fn++) {
                acc[fm][fn] = __builtin_amdgcn_mfma_f32_16x16x32_bf16(ah[fm], bh[fn], acc[fm][fn], 0,0,0);
                acc[fm][fn] = __builtin_amdgcn_mfma_f32_16x16x32_bf16(al[fm], bh[fn], acc[fm][fn], 0,0,0);
                acc[fm][fn] = __builtin_amdgcn_mfma_f32_16x16x32_bf16(ah[fm], bl[fn], acc[fm][fn], 0,0,0);
            }
    }

    // ---- epilogue: gate exchange via shfl_xor(8), cell update, h write ----
    const bool hiH = (lane & 8) != 0;
    const int u = lane & 7;
#pragma unroll
    for (int fm = 0; fm < 2; fm++) {
#pragma unroll
        for (int j = 0; j < 4; j++) {
            float v0 = acc[fm][0][j], v1 = acc[fm][1][j];
            float p0 = __shfl_xor(v0, 8);
            float p1 = __shfl_xor(v1, 8);
            float gi = (hiH ? p0 : v0) + bI;
            float gf = (hiH ? v0 : p0) + bF;
            float gg = (hiH ? p1 : v1) + bG;
            float go = (hiH ? v1 : p1) + bO;
            float cold = c_reg[fm*4 + j];
            float cn = sigm(gf)*cold + sigm(gi)*tanh_fast(gg);
            float hn = sigm(go)*tanh_fast(cn);
            c_reg[fm*4 + j] = cn;
            int m = w*32 + (lane >> 4)*4 + fm*16 + j;
            int gidx = (m0 + m)*HH + slice*8 + u;
            unsigned short hb = f2bf_rne(hn);
            Hh[gidx] = hb;
            Hl[gidx] = f2bf_rne(hn - bf2f(hb));
        }
    }
}

// ---- z = src_rows @ W_in^T + b_in (W_in row in regs per thread) ----
__device__ __forceinline__ void do_zproj(int wgz, int tid, const float* src, int stride, int coloff,
    const f32x4* wreg, float binreg, unsigned short* zh, unsigned short* zl,
    unsigned char* smem)
{
    float* xs = (float*)(smem + LDS_A_OFF);
    __syncthreads();
    int m0 = wgz * 8;
    {
        int r = tid >> 6, d = tid & 63;
        xs[r*64 + d] = src[(size_t)(m0 + r)*stride + coloff + d];
    }
    __syncthreads();
    int n = tid;
    float a[8];
#pragma unroll
    for (int r = 0; r < 8; r++) a[r] = binreg;
#pragma unroll
    for (int d4 = 0; d4 < 16; d4++) {
        f32x4 w4 = wreg[d4];
#pragma unroll
        for (int r = 0; r < 8; r++) {
            const float* xr = xs + r*64 + d4*4;
            a[r] += xr[0]*w4.x + xr[1]*w4.y + xr[2]*w4.z + xr[3]*w4.w;
        }
    }
#pragma unroll
    for (int r = 0; r < 8; r++) {
        unsigned short hb = f2bf_rne(a[r]);
        zh[(m0 + r)*HH + n] = hb;
        zl[(m0 + r)*HH + n] = f2bf_rne(a[r] - bf2f(hb));
    }
}

// ---- out(s) = h1 @ W_out^T + b_out (W_out K-slice in regs), also -> outbuf ----
__device__ __forceinline__ void do_outproj(int wgo, int tid, int s,
    const unsigned short* hh, const unsigned short* hl,
    const f32x4* wreg, const float* b_out, float* out, float* outbuf,
    unsigned char* smem)
{
    float* scr = (float*)(smem + LDS_A_OFF);
    __syncthreads();
    int m0 = wgo * 16;
#pragma unroll
    for (int i = 0; i < 16; i++) {
        int idx = i*512 + tid;
        int r = idx >> 9, k = idx & 511;
        int g = (m0 + r)*HH + k;
        scr[r*512 + k] = bf2f(hh[g]) + bf2f(hl[g]);
    }
    __syncthreads();
    int d = tid & 63, rb = tid >> 6;
    float p[16];
#pragma unroll
    for (int r = 0; r < 16; r++) p[r] = 0.f;
#pragma unroll
    for (int j4 = 0; j4 < 16; j4++) {
        f32x4 w4 = wreg[j4];
#pragma unroll
        for (int r = 0; r < 16; r++) {
            const float* hr = scr + r*512 + rb*64 + j4*4;
            p[r] += hr[0]*w4.x + hr[1]*w4.y + hr[2]*w4.z + hr[3]*w4.w;
        }
    }
    __syncthreads();
#pragma unroll
    for (int r = 0; r < 16; r++) scr[rb*1024 + r*64 + d] = p[r];
    __syncthreads();
#pragma unroll
    for (int o = 0; o < 2; o++) {
        int idx = o*512 + tid;
        int r = idx >> 6, dd = idx & 63;
        float a = b_out[dd];
#pragma unroll
        for (int q = 0; q < 8; q++) a += scr[q*1024 + r*64 + dd];
        out[(size_t)(m0 + r)*(T_TOT*64) + s*64 + dd] = a;
        outbuf[(m0 + r)*64 + dd] = a;
    }
}

// ---------------------------------------------------------------------------
__global__ __launch_bounds__(512, 2)
void persist(const float* __restrict__ x_hist, const float* __restrict__ W_in,
             const float* __restrict__ b_in,
             const unsigned short* __restrict__ Whi, const unsigned short* __restrict__ Wlo,
             const float* __restrict__ b01,
             const float* __restrict__ W_out, const float* __restrict__ b_out,
             unsigned short* zhi, unsigned short* zlo,
             unsigned short* h0hi, unsigned short* h0lo,
             unsigned short* h1hi, unsigned short* h1lo,
             float* outbuf, float* out, unsigned* cnt, unsigned* gen)
{
    extern __shared__ unsigned char smem[];
    const int wg = blockIdx.x, tid = threadIdx.x;
    const int layer = wg >> 7;
    const int id = wg & 127;
    const int slice = id >> 1;          // hu-slice: hu = slice*8+u
    const int m0 = (id & 1) * 256;      // batch half

    // ---- weights prologue: 4 regions (ih-hi, ih-lo, hh-hi, hh-lo), swizzled ----
    {
        const unsigned short* mats[4] = {
            Whi + ((size_t)layer << 20),
            Wlo + ((size_t)layer << 20),
            Whi + ((size_t)(2 + layer) << 20),
            Wlo + ((size_t)(2 + layer) << 20)
        };
#pragma unroll
        for (int reg = 0; reg < 4; reg++) {
            const unsigned short* src = mats[reg];
#pragma unroll
            for (int i = 0; i < 4; i++) {
                int uu = i*512 + tid;
                int row = uu >> 6, ds = uu & 63;
                int ss = ds ^ (row & 7);
                int grow = (row >> 3)*512 + slice*8 + (row & 7);
                bf16x8 v = *(const bf16x8*)(src + (size_t)grow*HH + ss*8);
                *(bf16x8*)(smem + reg*32768 + row*1024 + ds*16) = v;
            }
        }
    }

    const int lane = tid & 63;
    const int hu = slice*8 + (lane & 7);
    const float bI = b01[layer*2048 + hu];
    const float bF = b01[layer*2048 + 512 + hu];
    const float bG = b01[layer*2048 + 1024 + hu];
    const float bO = b01[layer*2048 + 1536 + hu];

    float c_reg[8];
#pragma unroll
    for (int i = 0; i < 8; i++) c_reg[i] = 0.f;

    f32x4 wreg[16];
    float binreg = 0.f;
    if (wg < 64) {
#pragma unroll
        for (int i = 0; i < 16; i++) wreg[i] = *(const f32x4*)(W_in + tid*64 + i*4);
        binreg = b_in[tid];
    } else if (wg >= 128 && wg < 160) {
        int od = tid & 63, orb = tid >> 6;
#pragma unroll
        for (int i = 0; i < 16; i++) wreg[i] = *(const f32x4*)(W_out + (size_t)od*HH + orb*64 + i*4);
    } else {
        f32x4 z = {0.f,0.f,0.f,0.f};
#pragma unroll
        for (int i = 0; i < 16; i++) wreg[i] = z;
    }

    for (int tick = 0; tick < 387; tick++) {
        if (tick == 0) {
            if (wg < 64)
                do_zproj(wg, tid, x_hist, 256*64, 0, wreg, binreg, zhi, zlo, smem);
        } else if (tick <= 257) {
            int tau = tick - 1;
            if (layer == 0) {
                if (tau < 256) {
                    int p = tau & 1, pm = (tau - 1) & 1;
                    do_gates(tid, m0, slice, zhi + p*SZ_HB, zlo + p*SZ_HB,
                             h0hi + pm*SZ_HB, h0lo + pm*SZ_HB,
                             bI,bF,bG,bO, c_reg, h0hi + p*SZ_HB, h0lo + p*SZ_HB, smem);
                }
                if (wg < 64 && tau + 1 < 256) {
                    int tt = tau + 1;
                    do_zproj(wg, tid, x_hist, 256*64, tt*64, wreg, binreg,
                             zhi + (tt&1)*SZ_HB, zlo + (tt&1)*SZ_HB, smem);
                }
            } else {
                int s = tau - 1;
                if (s >= 0) {
                    int p = s & 1, pm = (s - 1) & 1;
                    do_gates(tid, m0, slice, h0hi + p*SZ_HB, h0lo + p*SZ_HB,
                             h1hi + pm*SZ_HB, h1lo + pm*SZ_HB,
                             bI,bF,bG,bO, c_reg, h1hi + p*SZ_HB, h1lo + p*SZ_HB, smem);
                }
                if (wg >= 128 && wg < 160 && tau >= 2) {
                    int ss = tau - 2;
                    do_outproj(wg - 128, tid, ss, h1hi + (ss&1)*SZ_HB, h1lo + (ss&1)*SZ_HB,
                               wreg, b_out, out, outbuf, smem);
                }
            }
        } else if (tick <= 385) {
            int uu = tick - 258, ft = uu >> 2, ph = uu & 3, t = 256 + ft;
            if (ph == 0) {
                if (wg >= 128 && wg < 160)
                    do_outproj(wg - 128, tid, t - 1, h1hi + ((t-1)&1)*SZ_HB, h1lo + ((t-1)&1)*SZ_HB,
                               wreg, b_out, out, outbuf, smem);
            } else if (ph == 1) {
                if (wg < 64)
                    do_zproj(wg, tid, outbuf, 64, 0, wreg, binreg,
                             zhi + (t&1)*SZ_HB, zlo + (t&1)*SZ_HB, smem);
            } else if (ph == 2) {
                if (layer == 0) {
                    int p = t & 1, pm = (t - 1) & 1;
                    do_gates(tid, m0, slice, zhi + p*SZ_HB, zlo + p*SZ_HB,
                             h0hi + pm*SZ_HB, h0lo + pm*SZ_HB,
                             bI,bF,bG,bO, c_reg, h0hi + p*SZ_HB, h0lo + p*SZ_HB, smem);
                }
            } else {
                if (layer == 1) {
                    int p = t & 1, pm = (t - 1) & 1;
                    do_gates(tid, m0, slice, h0hi + p*SZ_HB, h0lo + p*SZ_HB,
                             h1hi + pm*SZ_HB, h1lo + pm*SZ_HB,
                             bI,bF,bG,bO, c_reg, h1hi + p*SZ_HB, h1lo + p*SZ_HB, smem);
                }
            }
        } else {
            if (wg >= 128 && wg < 160)
                do_outproj(wg - 128, tid, 287, h1hi + SZ_HB, h1lo + SZ_HB,
                           wreg, b_out, out, outbuf, smem);
        }
        gsync(tid, cnt, gen);
    }
}

// ---- prep kernels (unchanged from round 1) ----
__global__ void split_weights(const float* Wih, const float* Whh,
                              unsigned short* Whi, unsigned short* Wlo)
{
    int idx = (blockIdx.x*256 + threadIdx.x)*4;
    int m = idx >> 20;
    int off = idx & ((1 << 20) - 1);
    const float* src = (m < 2 ? Wih : Whh) + ((size_t)(m & 1) << 20) + off;
    float4 v = *(const float4*)(src);
    float vv[4] = {v.x, v.y, v.z, v.w};
#pragma unroll
    for (int j = 0; j < 4; j++) {
        unsigned short hb = f2bf_rne(vv[j]);
        Whi[idx + j] = hb;
        Wlo[idx + j] = f2bf_rne(vv[j] - bf2f(hb));
    }
}

__global__ void prep_bias(const float* bih, const float* bhh, float* b01)
{
    int i = blockIdx.x*256 + threadIdx.x;
    if (i < 4096) b01[i] = bih[i] + bhh[i];
}

// ---------------------------------------------------------------------------
extern "C" void kernel_launch(void* const* d_in, const int* in_sizes, int n_in,
                              void* d_out, int out_size, void* d_ws, size_t ws_size,
                              hipStream_t stream)
{
    (void)in_sizes; (void)n_in; (void)out_size; (void)ws_size;
    const float* x_hist = (const float*)d_in[0];
    const float* W_in   = (const float*)d_in[1];
    const float* b_in   = (const float*)d_in[2];
    const float* W_ih   = (const float*)d_in[3];
    const float* W_hh   = (const float*)d_in[4];
    const float* b_ih   = (const float*)d_in[5];
    const float* b_hh   = (const float*)d_in[6];
    const float* W_out  = (const float*)d_in[7];
    const float* b_out  = (const float*)d_in[8];
    float* out = (float*)d_out;

    uint8_t* ws = (uint8_t*)d_ws;
    size_t off = 0;
    auto alloc = [&](size_t bytes) -> void* {
        void* p = ws + off; off += (bytes + 255) & ~(size_t)255; return p;
    };
    unsigned short* Whi = (unsigned short*)alloc((size_t)4*(1 << 20)*2);
    unsigned short* Wlo = (unsigned short*)alloc((size_t)4*(1 << 20)*2);
    float*          b01 = (float*)alloc(4096*4);
    uint8_t* state_base = ws + off;
    unsigned short* zhi  = (unsigned short*)alloc((size_t)2*SZ_HB*2);
    unsigned short* zlo  = (unsigned short*)alloc((size_t)2*SZ_HB*2);
    unsigned short* h0hi = (unsigned short*)alloc((size_t)2*SZ_HB*2);
    unsigned short* h0lo = (unsigned short*)alloc((size_t)2*SZ_HB*2);
    unsigned short* h1hi = (unsigned short*)alloc((size_t)2*SZ_HB*2);
    unsigned short* h1lo = (unsigned short*)alloc((size_t)2*SZ_HB*2);
    float* outbuf = (float*)alloc((size_t)512*64*4);
    unsigned* sync = (unsigned*)alloc(256);
    size_t state_bytes = (size_t)((ws + off) - state_base);

    (void)hipFuncSetAttribute(reinterpret_cast<const void*>(persist),
                              hipFuncAttributeMaxDynamicSharedMemorySize, LDS_TOTAL);

    hipMemsetAsync(state_base, 0, state_bytes, stream);
    split_weights<<<4096, 256, 0, stream>>>(W_ih, W_hh, Whi, Wlo);
    prep_bias<<<16, 256, 0, stream>>>(b_ih, b_hh, b01);

    persist<<<256, 512, LDS_TOTAL, stream>>>(
        x_hist, W_in, b_in, Whi, Wlo, b01, W_out, b_out,
        zhi, zlo, h0hi, h0lo, h1hi, h1lo, outbuf, out,
        sync, sync + 32);
}

// Round 5
// 22976.460 us; speedup vs baseline: 1.7387x; 1.6215x over previous
//
#include <hip/hip_runtime.h>
#include <stdint.h>

#define FUTN 32
#define T_TOT 288
#define HH 512
#define SZ_HB (512*512)
#define LDS_A_OFF 131072
#define LDS_TOTAL 163840

typedef float f32x4 __attribute__((ext_vector_type(4)));
typedef __bf16 bf16x8 __attribute__((ext_vector_type(8)));

__device__ __forceinline__ unsigned short f2bf_rne(float x){
    union { float f; uint32_t u; } v; v.f = x;
    uint32_t r = v.u + 0x7FFFu + ((v.u >> 16) & 1u);
    return (unsigned short)(r >> 16);
}
__device__ __forceinline__ float bf2f(unsigned short b){
    union { uint32_t u; float f; } v; v.u = ((uint32_t)b) << 16;
    return v.f;
}
__device__ __forceinline__ float sigm(float x){ return 1.0f/(1.0f + __expf(-x)); }
__device__ __forceinline__ float tanh_fast(float x){ return 2.0f/(1.0f + __expf(-2.0f*x)) - 1.0f; }

// ---- grid-wide sync: agent-scope atomics (proven in round 2) ----
__device__ __forceinline__ void gsync(int tid, unsigned* cnt, unsigned* gen) {
    __syncthreads();
    if (tid == 0) {
        unsigned g = __hip_atomic_load(gen, __ATOMIC_RELAXED, __HIP_MEMORY_SCOPE_AGENT);
        unsigned old = __hip_atomic_fetch_add(cnt, 1u, __ATOMIC_ACQ_REL, __HIP_MEMORY_SCOPE_AGENT);
        if (old == 255u) {
            __hip_atomic_store(cnt, 0u, __ATOMIC_RELAXED, __HIP_MEMORY_SCOPE_AGENT);
            __hip_atomic_fetch_add(gen, 1u, __ATOMIC_RELEASE, __HIP_MEMORY_SCOPE_AGENT);
        } else {
            while (__hip_atomic_load(gen, __ATOMIC_RELAXED, __HIP_MEMORY_SCOPE_AGENT) == g)
                __builtin_amdgcn_s_sleep(2);
            (void)__hip_atomic_load(gen, __ATOMIC_ACQUIRE, __HIP_MEMORY_SCOPE_AGENT);
        }
    }
    __syncthreads();
}

struct Set { bf16x8 ah0, ah1, al0, al1, bh0, bh1, bl0, bl1; };

// ---------------------------------------------------------------------------
// Gates: A-fragments straight from global (L2) into VGPRs, ZERO barriers in
// the K-loop. B (weights hi/lo, ih/hh) resident in LDS, swizzled.
// 3-set rotating software pipeline, prefetch distance 2. c in registers.
// ---------------------------------------------------------------------------
__device__ __forceinline__ void do_gates(int tid, int m0, int slice,
    const unsigned short* A1h, const unsigned short* A1l,
    const unsigned short* A2h, const unsigned short* A2l,
    float bI, float bF, float bG, float bO,
    float* c_reg, unsigned short* Hh, unsigned short* Hl,
    unsigned char* smem)
{
    const int lane = tid & 63, w = tid >> 6;
    const size_t offF0 = (size_t)(m0 + w*32 + (lane & 15))*HH + ((lane >> 4) << 3);
    const size_t offF1 = offF0 + (size_t)16*HH;
    const int br0base = (lane & 15) * 1024;
    const int br1base = (16 + (lane & 15)) * 1024;
    const int sw = (lane & 15) & 7;
    const int ksb = lane >> 4;

    f32x4 acc[2][2];
#pragma unroll
    for (int a = 0; a < 2; a++)
#pragma unroll
        for (int b = 0; b < 2; b++) { f32x4 z = {0.f,0.f,0.f,0.f}; acc[a][b] = z; }

    Set s0, s1, s2;

#define LOAD_SET(S, KC) do { \
    const unsigned short* _sh = ((KC) < 16) ? A1h : A2h; \
    const unsigned short* _sl = ((KC) < 16) ? A1l : A2l; \
    const int _k = ((KC) & 15) * 32; \
    S.ah0 = *(const bf16x8*)(_sh + offF0 + _k); \
    S.ah1 = *(const bf16x8*)(_sh + offF1 + _k); \
    S.al0 = *(const bf16x8*)(_sl + offF0 + _k); \
    S.al1 = *(const bf16x8*)(_sl + offF1 + _k); \
    const int _mat = (KC) >> 4; \
    const int _ks = ((KC) & 15) * 4 + ksb; \
    const int _o0 = br0base + (((_ks) ^ sw) << 4); \
    const int _o1 = br1base + (((_ks) ^ sw) << 4); \
    S.bh0 = *(const bf16x8*)(smem + _mat*65536 + _o0); \
    S.bl0 = *(const bf16x8*)(smem + _mat*65536 + 32768 + _o0); \
    S.bh1 = *(const bf16x8*)(smem + _mat*65536 + _o1); \
    S.bl1 = *(const bf16x8*)(smem + _mat*65536 + 32768 + _o1); \
} while (0)

#define MFMA_SET(S) do { \
    acc[0][0] = __builtin_amdgcn_mfma_f32_16x16x32_bf16(S.ah0, S.bh0, acc[0][0], 0,0,0); \
    acc[0][0] = __builtin_amdgcn_mfma_f32_16x16x32_bf16(S.al0, S.bh0, acc[0][0], 0,0,0); \
    acc[0][0] = __builtin_amdgcn_mfma_f32_16x16x32_bf16(S.ah0, S.bl0, acc[0][0], 0,0,0); \
    acc[0][1] = __builtin_amdgcn_mfma_f32_16x16x32_bf16(S.ah0, S.bh1, acc[0][1], 0,0,0); \
    acc[0][1] = __builtin_amdgcn_mfma_f32_16x16x32_bf16(S.al0, S.bh1, acc[0][1], 0,0,0); \
    acc[0][1] = __builtin_amdgcn_mfma_f32_16x16x32_bf16(S.ah0, S.bl1, acc[0][1], 0,0,0); \
    acc[1][0] = __builtin_amdgcn_mfma_f32_16x16x32_bf16(S.ah1, S.bh0, acc[1][0], 0,0,0); \
    acc[1][0] = __builtin_amdgcn_mfma_f32_16x16x32_bf16(S.al1, S.bh0, acc[1][0], 0,0,0); \
    acc[1][0] = __builtin_amdgcn_mfma_f32_16x16x32_bf16(S.ah1, S.bl0, acc[1][0], 0,0,0); \
    acc[1][1] = __builtin_amdgcn_mfma_f32_16x16x32_bf16(S.ah1, S.bh1, acc[1][1], 0,0,0); \
    acc[1][1] = __builtin_amdgcn_mfma_f32_16x16x32_bf16(S.al1, S.bh1, acc[1][1], 0,0,0); \
    acc[1][1] = __builtin_amdgcn_mfma_f32_16x16x32_bf16(S.ah1, S.bl1, acc[1][1], 0,0,0); \
} while (0)

#define STEP(CUR, NXT, KC) do { if ((KC) + 2 < 32) LOAD_SET(NXT, (KC) + 2); MFMA_SET(CUR); } while (0)
#define STEP3(K) STEP(s0, s2, (K)); STEP(s1, s0, (K)+1); STEP(s2, s1, (K)+2)

    LOAD_SET(s0, 0);
    LOAD_SET(s1, 1);
    STEP3(0);  STEP3(3);  STEP3(6);  STEP3(9);  STEP3(12);
    STEP3(15); STEP3(18); STEP3(21); STEP3(24); STEP3(27);
    STEP(s0, s2, 30); STEP(s1, s0, 31);

#undef STEP3
#undef STEP
#undef MFMA_SET
#undef LOAD_SET

    // ---- epilogue: gate exchange via shfl_xor(8), cell update ----
    const bool hiH = (lane & 8) != 0;
    float hn_arr[2][4];
#pragma unroll
    for (int fm = 0; fm < 2; fm++)
#pragma unroll
        for (int j = 0; j < 4; j++) {
            float v0 = acc[fm][0][j], v1 = acc[fm][1][j];
            float p0 = __shfl_xor(v0, 8);
            float p1 = __shfl_xor(v1, 8);
            float gi = (hiH ? p0 : v0) + bI;
            float gf = (hiH ? v0 : p0) + bF;
            float gg = (hiH ? p1 : v1) + bG;
            float go = (hiH ? v1 : p1) + bO;
            float cold = c_reg[fm*4 + j];
            float cn = sigm(gf)*cold + sigm(gi)*tanh_fast(gg);
            float hn = sigm(go)*tanh_fast(cn);
            c_reg[fm*4 + j] = cn;
            hn_arr[fm][j] = hn;
        }

    // ---- transpose via LDS, coalesced 16B stores of h hi/lo ----
    __syncthreads();
    float* scr = (float*)(smem + LDS_A_OFF);   // [256][9] floats
    if (!(lane & 8)) {
#pragma unroll
        for (int fm = 0; fm < 2; fm++)
#pragma unroll
            for (int j = 0; j < 4; j++) {
                int m = w*32 + (lane >> 4)*4 + fm*16 + j;
                scr[m*9 + (lane & 7)] = hn_arr[fm][j];
            }
    }
    __syncthreads();
    {
        int row = tid & 255, part = tid >> 8;
        float v[8];
#pragma unroll
        for (int q = 0; q < 8; q++) v[q] = scr[row*9 + q];
        unsigned short h8[8];
        if (part == 0) {
#pragma unroll
            for (int q = 0; q < 8; q++) h8[q] = f2bf_rne(v[q]);
        } else {
#pragma unroll
            for (int q = 0; q < 8; q++) {
                unsigned short hb = f2bf_rne(v[q]);
                h8[q] = f2bf_rne(v[q] - bf2f(hb));
            }
        }
        uint4 pk;
        pk.x = (uint32_t)h8[0] | ((uint32_t)h8[1] << 16);
        pk.y = (uint32_t)h8[2] | ((uint32_t)h8[3] << 16);
        pk.z = (uint32_t)h8[4] | ((uint32_t)h8[5] << 16);
        pk.w = (uint32_t)h8[6] | ((uint32_t)h8[7] << 16);
        *(uint4*)((part ? Hl : Hh) + (size_t)(m0 + row)*HH + slice*8) = pk;
    }
}

// ---- z = src_rows @ W_in^T + b_in (W_in row in regs per thread) ----
__device__ __forceinline__ void do_zproj(int wgz, int tid, const float* src, int stride, int coloff,
    const f32x4* wreg, float binreg, unsigned short* zh, unsigned short* zl,
    unsigned char* smem)
{
    float* xs = (float*)(smem + LDS_A_OFF);
    __syncthreads();
    int m0 = wgz * 8;
    {
        int r = tid >> 6, d = tid & 63;
        xs[r*64 + d] = src[(size_t)(m0 + r)*stride + coloff + d];
    }
    __syncthreads();
    int n = tid;
    float a[8];
#pragma unroll
    for (int r = 0; r < 8; r++) a[r] = binreg;
#pragma unroll
    for (int d4 = 0; d4 < 16; d4++) {
        f32x4 w4 = wreg[d4];
#pragma unroll
        for (int r = 0; r < 8; r++) {
            const float* xr = xs + r*64 + d4*4;
            a[r] += xr[0]*w4.x + xr[1]*w4.y + xr[2]*w4.z + xr[3]*w4.w;
        }
    }
#pragma unroll
    for (int r = 0; r < 8; r++) {
        unsigned short hb = f2bf_rne(a[r]);
        zh[(m0 + r)*HH + n] = hb;
        zl[(m0 + r)*HH + n] = f2bf_rne(a[r] - bf2f(hb));
    }
}

// ---- out(s) = h1 @ W_out^T + b_out (W_out K-slice in regs), also -> outbuf ----
__device__ __forceinline__ void do_outproj(int wgo, int tid, int s,
    const unsigned short* hh, const unsigned short* hl,
    const f32x4* wreg, const float* b_out, float* out, float* outbuf,
    unsigned char* smem)
{
    float* scr = (float*)(smem + LDS_A_OFF);
    __syncthreads();
    int m0 = wgo * 16;
#pragma unroll
    for (int i = 0; i < 16; i++) {
        int idx = i*512 + tid;
        int r = idx >> 9, k = idx & 511;
        int g = (m0 + r)*HH + k;
        scr[r*512 + k] = bf2f(hh[g]) + bf2f(hl[g]);
    }
    __syncthreads();
    int d = tid & 63, rb = tid >> 6;
    float p[16];
#pragma unroll
    for (int r = 0; r < 16; r++) p[r] = 0.f;
#pragma unroll
    for (int j4 = 0; j4 < 16; j4++) {
        f32x4 w4 = wreg[j4];
#pragma unroll
        for (int r = 0; r < 16; r++) {
            const float* hr = scr + r*512 + rb*64 + j4*4;
            p[r] += hr[0]*w4.x + hr[1]*w4.y + hr[2]*w4.z + hr[3]*w4.w;
        }
    }
    __syncthreads();
#pragma unroll
    for (int r = 0; r < 16; r++) scr[rb*1024 + r*64 + d] = p[r];
    __syncthreads();
#pragma unroll
    for (int o = 0; o < 2; o++) {
        int idx = o*512 + tid;
        int r = idx >> 6, dd = idx & 63;
        float a = b_out[dd];
#pragma unroll
        for (int q = 0; q < 8; q++) a += scr[q*1024 + r*64 + dd];
        out[(size_t)(m0 + r)*(T_TOT*64) + s*64 + dd] = a;
        outbuf[(m0 + r)*64 + dd] = a;
    }
}

// ---------------------------------------------------------------------------
__global__ __launch_bounds__(512, 2)
void persist(const float* __restrict__ x_hist, const float* __restrict__ W_in,
             const float* __restrict__ b_in,
             const unsigned short* __restrict__ Whi, const unsigned short* __restrict__ Wlo,
             const float* __restrict__ b01,
             const float* __restrict__ W_out, const float* __restrict__ b_out,
             unsigned short* zhi, unsigned short* zlo,
             unsigned short* h0hi, unsigned short* h0lo,
             unsigned short* h1hi, unsigned short* h1lo,
             float* outbuf, float* out, unsigned* cnt, unsigned* gen)
{
    extern __shared__ unsigned char smem[];
    const int wg = blockIdx.x, tid = threadIdx.x;
    const int layer = wg >> 7;
    const int id = wg & 127;
    const int slice = id >> 1;          // hu-slice: hu = slice*8+u (64 slices)
    const int m0 = (id & 1) * 256;      // batch half

    // ---- weights prologue: 4 regions (ih-hi, ih-lo, hh-hi, hh-lo), swizzled ----
    {
        const unsigned short* mats[4] = {
            Whi + ((size_t)layer << 20),
            Wlo + ((size_t)layer << 20),
            Whi + ((size_t)(2 + layer) << 20),
            Wlo + ((size_t)(2 + layer) << 20)
        };
#pragma unroll
        for (int reg = 0; reg < 4; reg++) {
            const unsigned short* src = mats[reg];
#pragma unroll
            for (int i = 0; i < 4; i++) {
                int uu = i*512 + tid;
                int row = uu >> 6, ds = uu & 63;
                int ss = ds ^ (row & 7);
                int grow = (row >> 3)*512 + slice*8 + (row & 7);
                bf16x8 v = *(const bf16x8*)(src + (size_t)grow*HH + ss*8);
                *(bf16x8*)(smem + reg*32768 + row*1024 + ds*16) = v;
            }
        }
    }

    const int lane = tid & 63;
    const int hu = slice*8 + (lane & 7);
    const float bI = b01[layer*2048 + hu];
    const float bF = b01[layer*2048 + 512 + hu];
    const float bG = b01[layer*2048 + 1024 + hu];
    const float bO = b01[layer*2048 + 1536 + hu];

    float c_reg[8];
#pragma unroll
    for (int i = 0; i < 8; i++) c_reg[i] = 0.f;

    f32x4 wreg[16];
    float binreg = 0.f;
    if (wg < 64) {
#pragma unroll
        for (int i = 0; i < 16; i++) wreg[i] = *(const f32x4*)(W_in + tid*64 + i*4);
        binreg = b_in[tid];
    } else if (wg >= 128 && wg < 160) {
        int od = tid & 63, orb = tid >> 6;
#pragma unroll
        for (int i = 0; i < 16; i++) wreg[i] = *(const f32x4*)(W_out + (size_t)od*HH + orb*64 + i*4);
    } else {
        f32x4 z = {0.f,0.f,0.f,0.f};
#pragma unroll
        for (int i = 0; i < 16; i++) wreg[i] = z;
    }

    for (int tick = 0; tick < 387; tick++) {
        if (tick == 0) {
            if (wg < 64)
                do_zproj(wg, tid, x_hist, 256*64, 0, wreg, binreg, zhi, zlo, smem);
        } else if (tick <= 257) {
            int tau = tick - 1;
            if (layer == 0) {
                if (tau < 256) {
                    int p = tau & 1, pm = (tau - 1) & 1;
                    do_gates(tid, m0, slice, zhi + p*SZ_HB, zlo + p*SZ_HB,
                             h0hi + pm*SZ_HB, h0lo + pm*SZ_HB,
                             bI,bF,bG,bO, c_reg, h0hi + p*SZ_HB, h0lo + p*SZ_HB, smem);
                }
                if (wg < 64 && tau + 1 < 256) {
                    int tt = tau + 1;
                    do_zproj(wg, tid, x_hist, 256*64, tt*64, wreg, binreg,
                             zhi + (tt&1)*SZ_HB, zlo + (tt&1)*SZ_HB, smem);
                }
            } else {
                int s = tau - 1;
                if (s >= 0) {
                    int p = s & 1, pm = (s - 1) & 1;
                    do_gates(tid, m0, slice, h0hi + p*SZ_HB, h0lo + p*SZ_HB,
                             h1hi + pm*SZ_HB, h1lo + pm*SZ_HB,
                             bI,bF,bG,bO, c_reg, h1hi + p*SZ_HB, h1lo + p*SZ_HB, smem);
                }
                if (wg >= 128 && wg < 160 && tau >= 2) {
                    int ss = tau - 2;
                    do_outproj(wg - 128, tid, ss, h1hi + (ss&1)*SZ_HB, h1lo + (ss&1)*SZ_HB,
                               wreg, b_out, out, outbuf, smem);
                }
            }
        } else if (tick <= 385) {
            int uu = tick - 258, ft = uu >> 2, ph = uu & 3, t = 256 + ft;
            if (ph == 0) {
                if (wg >= 128 && wg < 160)
                    do_outproj(wg - 128, tid, t - 1, h1hi + ((t-1)&1)*SZ_HB, h1lo + ((t-1)&1)*SZ_HB,
                               wreg, b_out, out, outbuf, smem);
            } else if (ph == 1) {
                if (wg < 64)
                    do_zproj(wg, tid, outbuf, 64, 0, wreg, binreg,
                             zhi + (t&1)*SZ_HB, zlo + (t&1)*SZ_HB, smem);
            } else if (ph == 2) {
                if (layer == 0) {
                    int p = t & 1, pm = (t - 1) & 1;
                    do_gates(tid, m0, slice, zhi + p*SZ_HB, zlo + p*SZ_HB,
                             h0hi + pm*SZ_HB, h0lo + pm*SZ_HB,
                             bI,bF,bG,bO, c_reg, h0hi + p*SZ_HB, h0lo + p*SZ_HB, smem);
                }
            } else {
                if (layer == 1) {
                    int p = t & 1, pm = (t - 1) & 1;
                    do_gates(tid, m0, slice, h0hi + p*SZ_HB, h0lo + p*SZ_HB,
                             h1hi + pm*SZ_HB, h1lo + pm*SZ_HB,
                             bI,bF,bG,bO, c_reg, h1hi + p*SZ_HB, h1lo + p*SZ_HB, smem);
                }
            }
        } else {
            if (wg >= 128 && wg < 160)
                do_outproj(wg - 128, tid, 287, h1hi + SZ_HB, h1lo + SZ_HB,
                           wreg, b_out, out, outbuf, smem);
        }
        gsync(tid, cnt, gen);
    }
}

// ---- prep kernels ----
__global__ void split_weights(const float* Wih, const float* Whh,
                              unsigned short* Whi, unsigned short* Wlo)
{
    int idx = (blockIdx.x*256 + threadIdx.x)*4;
    int m = idx >> 20;
    int off = idx & ((1 << 20) - 1);
    const float* src = (m < 2 ? Wih : Whh) + ((size_t)(m & 1) << 20) + off;
    float4 v = *(const float4*)(src);
    float vv[4] = {v.x, v.y, v.z, v.w};
#pragma unroll
    for (int j = 0; j < 4; j++) {
        unsigned short hb = f2bf_rne(vv[j]);
        Whi[idx + j] = hb;
        Wlo[idx + j] = f2bf_rne(vv[j] - bf2f(hb));
    }
}

__global__ void prep_bias(const float* bih, const float* bhh, float* b01)
{
    int i = blockIdx.x*256 + threadIdx.x;
    if (i < 4096) b01[i] = bih[i] + bhh[i];
}

// ---------------------------------------------------------------------------
extern "C" void kernel_launch(void* const* d_in, const int* in_sizes, int n_in,
                              void* d_out, int out_size, void* d_ws, size_t ws_size,
                              hipStream_t stream)
{
    (void)in_sizes; (void)n_in; (void)out_size; (void)ws_size;
    const float* x_hist = (const float*)d_in[0];
    const float* W_in   = (const float*)d_in[1];
    const float* b_in   = (const float*)d_in[2];
    const float* W_ih   = (const float*)d_in[3];
    const float* W_hh   = (const float*)d_in[4];
    const float* b_ih   = (const float*)d_in[5];
    const float* b_hh   = (const float*)d_in[6];
    const float* W_out  = (const float*)d_in[7];
    const float* b_out  = (const float*)d_in[8];
    float* out = (float*)d_out;

    uint8_t* ws = (uint8_t*)d_ws;
    size_t off = 0;
    auto alloc = [&](size_t bytes) -> void* {
        void* p = ws + off; off += (bytes + 255) & ~(size_t)255; return p;
    };
    unsigned short* Whi = (unsigned short*)alloc((size_t)4*(1 << 20)*2);
    unsigned short* Wlo = (unsigned short*)alloc((size_t)4*(1 << 20)*2);
    float*          b01 = (float*)alloc(4096*4);
    uint8_t* state_base = ws + off;
    unsigned short* zhi  = (unsigned short*)alloc((size_t)2*SZ_HB*2);
    unsigned short* zlo  = (unsigned short*)alloc((size_t)2*SZ_HB*2);
    unsigned short* h0hi = (unsigned short*)alloc((size_t)2*SZ_HB*2);
    unsigned short* h0lo = (unsigned short*)alloc((size_t)2*SZ_HB*2);
    unsigned short* h1hi = (unsigned short*)alloc((size_t)2*SZ_HB*2);
    unsigned short* h1lo = (unsigned short*)alloc((size_t)2*SZ_HB*2);
    float* outbuf = (float*)alloc((size_t)512*64*4);
    unsigned* sync = (unsigned*)alloc(256);
    size_t state_bytes = (size_t)((ws + off) - state_base);

    (void)hipFuncSetAttribute(reinterpret_cast<const void*>(persist),
                              hipFuncAttributeMaxDynamicSharedMemorySize, LDS_TOTAL);

    hipMemsetAsync(state_base, 0, state_bytes, stream);
    split_weights<<<4096, 256, 0, stream>>>(W_ih, W_hh, Whi, Wlo);
    prep_bias<<<16, 256, 0, stream>>>(b_ih, b_hh, b01);

    persist<<<256, 512, LDS_TOTAL, stream>>>(
        x_hist, W_in, b_in, Whi, Wlo, b01, W_out, b_out,
        zhi, zlo, h0hi, h0lo, h1hi, h1lo, outbuf, out,
        sync, sync + 32);
}

// Round 6
// 16653.482 us; speedup vs baseline: 2.3989x; 1.3797x over previous
//
#include <hip/hip_runtime.h>
#include <stdint.h>

#define FUTN 32
#define T_TOT 288
#define HH 512
#define SZ_HB (512*512)
#define LDS_A_OFF 131072
#define LDS_TOTAL 163840

typedef float f32x4 __attribute__((ext_vector_type(4)));
typedef __bf16 bf16x8 __attribute__((ext_vector_type(8)));

__device__ __forceinline__ unsigned short f2bf_rne(float x){
    union { float f; uint32_t u; } v; v.f = x;
    uint32_t r = v.u + 0x7FFFu + ((v.u >> 16) & 1u);
    return (unsigned short)(r >> 16);
}
__device__ __forceinline__ float bf2f(unsigned short b){
    union { uint32_t u; float f; } v; v.u = ((uint32_t)b) << 16;
    return v.f;
}
__device__ __forceinline__ float sigm(float x){ return 1.0f/(1.0f + __expf(-x)); }
__device__ __forceinline__ float tanh_fast(float x){ return 2.0f/(1.0f + __expf(-2.0f*x)) - 1.0f; }

// ---------------------------------------------------------------------------
// Two-level grid sync. Members: relaxed arrive (NO L2 ops) + L1-only inv on
// wake. Per-XCD leader (last local arriver; exactly 32 WGs/XCD since grid=256
// is 1 WG/CU co-resident): ONE buffer_wbl2 (agent release fence), 8-way global
// handshake, ONE L2 inv (agent acquire fence). Replaces 256 agent-scope
// ACQ_REL per tick (= per-WG L2 writeback+invalidate storm) with 1+1 per XCD.
// ---------------------------------------------------------------------------
__device__ __forceinline__ unsigned xcc_id() {
    // HW_REG_XCC_ID = 20, offset 0, size 8  [measured working on gfx950, m09]
    return __builtin_amdgcn_s_getreg(20 | (7 << 11)) & 7u;
}

__device__ __forceinline__ void gsync2(int tid, unsigned* sy) {
    __syncthreads();
    if (tid == 0) {
        asm volatile("" ::: "memory");
        unsigned x = xcc_id();
        unsigned* gen  = sy;                 // global generation
        unsigned* gcnt = sy + 32;            // global (per-XCD-leader) counter
        unsigned* lcnt = sy + 64  + 32 * x;  // per-XCD arrival counter
        unsigned* lgen = sy + 320 + 32 * x;  // per-XCD generation
        unsigned g  = __hip_atomic_load(gen,  __ATOMIC_RELAXED, __HIP_MEMORY_SCOPE_AGENT);
        unsigned lg = __hip_atomic_load(lgen, __ATOMIC_RELAXED, __HIP_MEMORY_SCOPE_AGENT);
        // my WG's stores must be in (XCD-shared) L2 before I declare arrival:
        __builtin_amdgcn_fence(__ATOMIC_RELEASE, "workgroup");   // waitcnt only
        unsigned old = __hip_atomic_fetch_add(lcnt, 1u, __ATOMIC_RELAXED, __HIP_MEMORY_SCOPE_AGENT);
        if (old == 31u) {
            // ---- XCD leader ----
            __hip_atomic_store(lcnt, 0u, __ATOMIC_RELAXED, __HIP_MEMORY_SCOPE_AGENT);
            // flush this XCD's L2 (all 32 co-resident WGs' writes) to LLC:
            __builtin_amdgcn_fence(__ATOMIC_RELEASE, "agent");   // buffer_wbl2
            unsigned o2 = __hip_atomic_fetch_add(gcnt, 1u, __ATOMIC_RELAXED, __HIP_MEMORY_SCOPE_AGENT);
            if (o2 == 7u) {
                __hip_atomic_store(gcnt, 0u, __ATOMIC_RELAXED, __HIP_MEMORY_SCOPE_AGENT);
                __hip_atomic_fetch_add(gen, 1u, __ATOMIC_RELAXED, __HIP_MEMORY_SCOPE_AGENT);
            } else {
                while (__hip_atomic_load(gen, __ATOMIC_RELAXED, __HIP_MEMORY_SCOPE_AGENT) == g)
                    __builtin_amdgcn_s_sleep(2);
            }
            // all 8 XCDs flushed -> invalidate local L2, then release my XCD:
            __builtin_amdgcn_fence(__ATOMIC_ACQUIRE, "agent");   // buffer_inv (L1+L2)
            __hip_atomic_fetch_add(lgen, 1u, __ATOMIC_RELAXED, __HIP_MEMORY_SCOPE_AGENT);
        } else {
            while (__hip_atomic_load(lgen, __ATOMIC_RELAXED, __HIP_MEMORY_SCOPE_AGENT) == lg)
                __builtin_amdgcn_s_sleep(2);
            // leader already invalidated the XCD L2; clear this CU's L1 only:
            asm volatile("buffer_inv" ::: "memory");
            asm volatile("s_waitcnt vmcnt(0)" ::: "memory");
        }
        asm volatile("" ::: "memory");
    }
    __syncthreads();
}

struct Set { bf16x8 ah0, ah1, al0, al1, bh0, bh1, bl0, bl1; };

// ---------------------------------------------------------------------------
// Gates: A-fragments straight from global (now L2-served) into VGPRs, zero
// barriers in the K-loop. B (weights hi/lo, ih/hh) resident in LDS, swizzled.
// 3-set rotating software pipeline, prefetch distance 2. c in registers.
// (unchanged from round 5)
// ---------------------------------------------------------------------------
__device__ __forceinline__ void do_gates(int tid, int m0, int slice,
    const unsigned short* A1h, const unsigned short* A1l,
    const unsigned short* A2h, const unsigned short* A2l,
    float bI, float bF, float bG, float bO,
    float* c_reg, unsigned short* Hh, unsigned short* Hl,
    unsigned char* smem)
{
    const int lane = tid & 63, w = tid >> 6;
    const size_t offF0 = (size_t)(m0 + w*32 + (lane & 15))*HH + ((lane >> 4) << 3);
    const size_t offF1 = offF0 + (size_t)16*HH;
    const int br0base = (lane & 15) * 1024;
    const int br1base = (16 + (lane & 15)) * 1024;
    const int sw = (lane & 15) & 7;
    const int ksb = lane >> 4;

    f32x4 acc[2][2];
#pragma unroll
    for (int a = 0; a < 2; a++)
#pragma unroll
        for (int b = 0; b < 2; b++) { f32x4 z = {0.f,0.f,0.f,0.f}; acc[a][b] = z; }

    Set s0, s1, s2;

#define LOAD_SET(S, KC) do { \
    const unsigned short* _sh = ((KC) < 16) ? A1h : A2h; \
    const unsigned short* _sl = ((KC) < 16) ? A1l : A2l; \
    const int _k = ((KC) & 15) * 32; \
    S.ah0 = *(const bf16x8*)(_sh + offF0 + _k); \
    S.ah1 = *(const bf16x8*)(_sh + offF1 + _k); \
    S.al0 = *(const bf16x8*)(_sl + offF0 + _k); \
    S.al1 = *(const bf16x8*)(_sl + offF1 + _k); \
    const int _mat = (KC) >> 4; \
    const int _ks = ((KC) & 15) * 4 + ksb; \
    const int _o0 = br0base + (((_ks) ^ sw) << 4); \
    const int _o1 = br1base + (((_ks) ^ sw) << 4); \
    S.bh0 = *(const bf16x8*)(smem + _mat*65536 + _o0); \
    S.bl0 = *(const bf16x8*)(smem + _mat*65536 + 32768 + _o0); \
    S.bh1 = *(const bf16x8*)(smem + _mat*65536 + _o1); \
    S.bl1 = *(const bf16x8*)(smem + _mat*65536 + 32768 + _o1); \
} while (0)

#define MFMA_SET(S) do { \
    acc[0][0] = __builtin_amdgcn_mfma_f32_16x16x32_bf16(S.ah0, S.bh0, acc[0][0], 0,0,0); \
    acc[0][0] = __builtin_amdgcn_mfma_f32_16x16x32_bf16(S.al0, S.bh0, acc[0][0], 0,0,0); \
    acc[0][0] = __builtin_amdgcn_mfma_f32_16x16x32_bf16(S.ah0, S.bl0, acc[0][0], 0,0,0); \
    acc[0][1] = __builtin_amdgcn_mfma_f32_16x16x32_bf16(S.ah0, S.bh1, acc[0][1], 0,0,0); \
    acc[0][1] = __builtin_amdgcn_mfma_f32_16x16x32_bf16(S.al0, S.bh1, acc[0][1], 0,0,0); \
    acc[0][1] = __builtin_amdgcn_mfma_f32_16x16x32_bf16(S.ah0, S.bl1, acc[0][1], 0,0,0); \
    acc[1][0] = __builtin_amdgcn_mfma_f32_16x16x32_bf16(S.ah1, S.bh0, acc[1][0], 0,0,0); \
    acc[1][0] = __builtin_amdgcn_mfma_f32_16x16x32_bf16(S.al1, S.bh0, acc[1][0], 0,0,0); \
    acc[1][0] = __builtin_amdgcn_mfma_f32_16x16x32_bf16(S.ah1, S.bl0, acc[1][0], 0,0,0); \
    acc[1][1] = __builtin_amdgcn_mfma_f32_16x16x32_bf16(S.ah1, S.bh1, acc[1][1], 0,0,0); \
    acc[1][1] = __builtin_amdgcn_mfma_f32_16x16x32_bf16(S.al1, S.bh1, acc[1][1], 0,0,0); \
    acc[1][1] = __builtin_amdgcn_mfma_f32_16x16x32_bf16(S.ah1, S.bl1, acc[1][1], 0,0,0); \
} while (0)

#define STEP(CUR, NXT, KC) do { if ((KC) + 2 < 32) LOAD_SET(NXT, (KC) + 2); MFMA_SET(CUR); } while (0)
#define STEP3(K) STEP(s0, s2, (K)); STEP(s1, s0, (K)+1); STEP(s2, s1, (K)+2)

    LOAD_SET(s0, 0);
    LOAD_SET(s1, 1);
    STEP3(0);  STEP3(3);  STEP3(6);  STEP3(9);  STEP3(12);
    STEP3(15); STEP3(18); STEP3(21); STEP3(24); STEP3(27);
    STEP(s0, s2, 30); STEP(s1, s0, 31);

#undef STEP3
#undef STEP
#undef MFMA_SET
#undef LOAD_SET

    // ---- epilogue: gate exchange via shfl_xor(8), cell update ----
    const bool hiH = (lane & 8) != 0;
    float hn_arr[2][4];
#pragma unroll
    for (int fm = 0; fm < 2; fm++)
#pragma unroll
        for (int j = 0; j < 4; j++) {
            float v0 = acc[fm][0][j], v1 = acc[fm][1][j];
            float p0 = __shfl_xor(v0, 8);
            float p1 = __shfl_xor(v1, 8);
            float gi = (hiH ? p0 : v0) + bI;
            float gf = (hiH ? v0 : p0) + bF;
            float gg = (hiH ? p1 : v1) + bG;
            float go = (hiH ? v1 : p1) + bO;
            float cold = c_reg[fm*4 + j];
            float cn = sigm(gf)*cold + sigm(gi)*tanh_fast(gg);
            float hn = sigm(go)*tanh_fast(cn);
            c_reg[fm*4 + j] = cn;
            hn_arr[fm][j] = hn;
        }

    // ---- transpose via LDS, coalesced 16B stores of h hi/lo ----
    __syncthreads();
    float* scr = (float*)(smem + LDS_A_OFF);   // [256][9] floats
    if (!(lane & 8)) {
#pragma unroll
        for (int fm = 0; fm < 2; fm++)
#pragma unroll
            for (int j = 0; j < 4; j++) {
                int m = w*32 + (lane >> 4)*4 + fm*16 + j;
                scr[m*9 + (lane & 7)] = hn_arr[fm][j];
            }
    }
    __syncthreads();
    {
        int row = tid & 255, part = tid >> 8;
        float v[8];
#pragma unroll
        for (int q = 0; q < 8; q++) v[q] = scr[row*9 + q];
        unsigned short h8[8];
        if (part == 0) {
#pragma unroll
            for (int q = 0; q < 8; q++) h8[q] = f2bf_rne(v[q]);
        } else {
#pragma unroll
            for (int q = 0; q < 8; q++) {
                unsigned short hb = f2bf_rne(v[q]);
                h8[q] = f2bf_rne(v[q] - bf2f(hb));
            }
        }
        uint4 pk;
        pk.x = (uint32_t)h8[0] | ((uint32_t)h8[1] << 16);
        pk.y = (uint32_t)h8[2] | ((uint32_t)h8[3] << 16);
        pk.z = (uint32_t)h8[4] | ((uint32_t)h8[5] << 16);
        pk.w = (uint32_t)h8[6] | ((uint32_t)h8[7] << 16);
        *(uint4*)((part ? Hl : Hh) + (size_t)(m0 + row)*HH + slice*8) = pk;
    }
}

// ---- z = src_rows @ W_in^T + b_in (W_in row in regs per thread), 8 rows/WG ----
__device__ __forceinline__ void do_zproj(int wgz, int tid, const float* src, int stride, int coloff,
    const f32x4* wreg, float binreg, unsigned short* zh, unsigned short* zl,
    unsigned char* smem)
{
    float* xs = (float*)(smem + LDS_A_OFF);
    __syncthreads();
    int m0 = wgz * 8;
    {
        int r = tid >> 6, d = tid & 63;
        xs[r*64 + d] = src[(size_t)(m0 + r)*stride + coloff + d];
    }
    __syncthreads();
    int n = tid;
    float a[8];
#pragma unroll
    for (int r = 0; r < 8; r++) a[r] = binreg;
#pragma unroll
    for (int d4 = 0; d4 < 16; d4++) {
        f32x4 w4 = wreg[d4];
#pragma unroll
        for (int r = 0; r < 8; r++) {
            const float* xr = xs + r*64 + d4*4;
            a[r] += xr[0]*w4.x + xr[1]*w4.y + xr[2]*w4.z + xr[3]*w4.w;
        }
    }
#pragma unroll
    for (int r = 0; r < 8; r++) {
        unsigned short hb = f2bf_rne(a[r]);
        zh[(m0 + r)*HH + n] = hb;
        zl[(m0 + r)*HH + n] = f2bf_rne(a[r] - bf2f(hb));
    }
}

// ---- out(s) = h1 @ W_out^T + b_out, 8 rows/WG (64 WGs), W_out slice in regs ----
__device__ __forceinline__ void do_outproj(int wgo, int tid, int s,
    const unsigned short* hh, const unsigned short* hl,
    const f32x4* wreg, const float* b_out, float* out, float* outbuf,
    unsigned char* smem)
{
    float* scr = (float*)(smem + LDS_A_OFF);   // [8][512] staged h (16 KB)
    float* par = scr + 8*512;                  // [8 rb][8 r][64 d] partials (16 KB)
    __syncthreads();
    int m0 = wgo * 8;
#pragma unroll
    for (int i = 0; i < 8; i++) {
        int idx = i*512 + tid;
        int r = idx >> 9, k = idx & 511;
        int g = (m0 + r)*HH + k;
        scr[idx] = bf2f(hh[g]) + bf2f(hl[g]);
    }
    __syncthreads();
    int d = tid & 63, rb = tid >> 6;
    float p[8];
#pragma unroll
    for (int r = 0; r < 8; r++) p[r] = 0.f;
#pragma unroll
    for (int j4 = 0; j4 < 16; j4++) {
        f32x4 w4 = wreg[j4];
#pragma unroll
        for (int r = 0; r < 8; r++) {
            const float* hr = scr + r*512 + rb*64 + j4*4;
            p[r] += hr[0]*w4.x + hr[1]*w4.y + hr[2]*w4.z + hr[3]*w4.w;
        }
    }
#pragma unroll
    for (int r = 0; r < 8; r++) par[rb*512 + r*64 + d] = p[r];
    __syncthreads();
    {
        int r = tid >> 6, dd = tid & 63;
        float a = b_out[dd];
#pragma unroll
        for (int q = 0; q < 8; q++) a += par[q*512 + r*64 + dd];
        out[(size_t)(m0 + r)*(T_TOT*64) + s*64 + dd] = a;
        outbuf[(m0 + r)*64 + dd] = a;
    }
}

// ---------------------------------------------------------------------------
// Roles: gates0 = WGs 0-127, gates1 = WGs 128-255.
// Side jobs off the hot WGs: outproj -> WGs 0-63 (layer 0), zproj -> WGs
// 160-223 (layer 1), so no WG runs gates + two extra jobs.
// ---------------------------------------------------------------------------
__global__ __launch_bounds__(512, 2)
void persist(const float* __restrict__ x_hist, const float* __restrict__ W_in,
             const float* __restrict__ b_in,
             const unsigned short* __restrict__ Whi, const unsigned short* __restrict__ Wlo,
             const float* __restrict__ b01,
             const float* __restrict__ W_out, const float* __restrict__ b_out,
             unsigned short* zhi, unsigned short* zlo,
             unsigned short* h0hi, unsigned short* h0lo,
             unsigned short* h1hi, unsigned short* h1lo,
             float* outbuf, float* out, unsigned* sy)
{
    extern __shared__ unsigned char smem[];
    const int wg = blockIdx.x, tid = threadIdx.x;
    const int layer = wg >> 7;
    const int id = wg & 127;
    const int slice = id >> 1;          // hu-slice: hu = slice*8+u (64 slices)
    const int m0 = (id & 1) * 256;      // batch half

    // ---- weights prologue: 4 regions (ih-hi, ih-lo, hh-hi, hh-lo), swizzled ----
    {
        const unsigned short* mats[4] = {
            Whi + ((size_t)layer << 20),
            Wlo + ((size_t)layer << 20),
            Whi + ((size_t)(2 + layer) << 20),
            Wlo + ((size_t)(2 + layer) << 20)
        };
#pragma unroll
        for (int reg = 0; reg < 4; reg++) {
            const unsigned short* src = mats[reg];
#pragma unroll
            for (int i = 0; i < 4; i++) {
                int uu = i*512 + tid;
                int row = uu >> 6, ds = uu & 63;
                int ss = ds ^ (row & 7);
                int grow = (row >> 3)*512 + slice*8 + (row & 7);
                bf16x8 v = *(const bf16x8*)(src + (size_t)grow*HH + ss*8);
                *(bf16x8*)(smem + reg*32768 + row*1024 + ds*16) = v;
            }
        }
    }

    const int lane = tid & 63;
    const int hu = slice*8 + (lane & 7);
    const float bI = b01[layer*2048 + hu];
    const float bF = b01[layer*2048 + 512 + hu];
    const float bG = b01[layer*2048 + 1024 + hu];
    const float bO = b01[layer*2048 + 1536 + hu];

    float c_reg[8];
#pragma unroll
    for (int i = 0; i < 8; i++) c_reg[i] = 0.f;

    f32x4 wreg[16];
    float binreg = 0.f;
    if (wg < 64) {                       // outproj WGs: W_out K-slice
        int od = tid & 63, orb = tid >> 6;
#pragma unroll
        for (int i = 0; i < 16; i++) wreg[i] = *(const f32x4*)(W_out + (size_t)od*HH + orb*64 + i*4);
    } else if (wg >= 160 && wg < 224) {  // zproj WGs: W_in row
#pragma unroll
        for (int i = 0; i < 16; i++) wreg[i] = *(const f32x4*)(W_in + tid*64 + i*4);
        binreg = b_in[tid];
    } else {
        f32x4 z = {0.f,0.f,0.f,0.f};
#pragma unroll
        for (int i = 0; i < 16; i++) wreg[i] = z;
    }

    for (int tick = 0; tick < 387; tick++) {
        if (tick == 0) {
            if (wg >= 160 && wg < 224)
                do_zproj(wg - 160, tid, x_hist, 256*64, 0, wreg, binreg, zhi, zlo, smem);
        } else if (tick <= 257) {
            int tau = tick - 1;
            if (layer == 0) {
                if (tau < 256) {
                    int p = tau & 1, pm = (tau - 1) & 1;
                    do_gates(tid, m0, slice, zhi + p*SZ_HB, zlo + p*SZ_HB,
                             h0hi + pm*SZ_HB, h0lo + pm*SZ_HB,
                             bI,bF,bG,bO, c_reg, h0hi + p*SZ_HB, h0lo + p*SZ_HB, smem);
                }
                if (wg < 64 && tau >= 2) {
                    int ss = tau - 2;
                    do_outproj(wg, tid, ss, h1hi + (ss&1)*SZ_HB, h1lo + (ss&1)*SZ_HB,
                               wreg, b_out, out, outbuf, smem);
                }
            } else {
                if (tau >= 1) {
                    int s = tau - 1;
                    int p = s & 1, pm = (s - 1) & 1;
                    do_gates(tid, m0, slice, h0hi + p*SZ_HB, h0lo + p*SZ_HB,
                             h1hi + pm*SZ_HB, h1lo + pm*SZ_HB,
                             bI,bF,bG,bO, c_reg, h1hi + p*SZ_HB, h1lo + p*SZ_HB, smem);
                }
                if (wg >= 160 && wg < 224 && tau + 1 < 256) {
                    int tt = tau + 1;
                    do_zproj(wg - 160, tid, x_hist, 256*64, tt*64, wreg, binreg,
                             zhi + (tt&1)*SZ_HB, zlo + (tt&1)*SZ_HB, smem);
                }
            }
        } else if (tick <= 385) {
            int uu = tick - 258, ft = uu >> 2, ph = uu & 3, t = 256 + ft;
            if (ph == 0) {
                if (wg < 64)
                    do_outproj(wg, tid, t - 1, h1hi + ((t-1)&1)*SZ_HB, h1lo + ((t-1)&1)*SZ_HB,
                               wreg, b_out, out, outbuf, smem);
            } else if (ph == 1) {
                if (wg >= 160 && wg < 224)
                    do_zproj(wg - 160, tid, outbuf, 64, 0, wreg, binreg,
                             zhi + (t&1)*SZ_HB, zlo + (t&1)*SZ_HB, smem);
            } else if (ph == 2) {
                if (layer == 0) {
                    int p = t & 1, pm = (t - 1) & 1;
                    do_gates(tid, m0, slice, zhi + p*SZ_HB, zlo + p*SZ_HB,
                             h0hi + pm*SZ_HB, h0lo + pm*SZ_HB,
                             bI,bF,bG,bO, c_reg, h0hi + p*SZ_HB, h0lo + p*SZ_HB, smem);
                }
            } else {
                if (layer == 1) {
                    int p = t & 1, pm = (t - 1) & 1;
                    do_gates(tid, m0, slice, h0hi + p*SZ_HB, h0lo + p*SZ_HB,
                             h1hi + pm*SZ_HB, h1lo + pm*SZ_HB,
                             bI,bF,bG,bO, c_reg, h1hi + p*SZ_HB, h1lo + p*SZ_HB, smem);
                }
            }
        } else {
            if (wg < 64)
                do_outproj(wg, tid, 287, h1hi + SZ_HB, h1lo + SZ_HB,
                           wreg, b_out, out, outbuf, smem);
        }
        gsync2(tid, sy);
    }
}

// ---- prep kernels ----
__global__ void split_weights(const float* Wih, const float* Whh,
                              unsigned short* Whi, unsigned short* Wlo)
{
    int idx = (blockIdx.x*256 + threadIdx.x)*4;
    int m = idx >> 20;
    int off = idx & ((1 << 20) - 1);
    const float* src = (m < 2 ? Wih : Whh) + ((size_t)(m & 1) << 20) + off;
    float4 v = *(const float4*)(src);
    float vv[4] = {v.x, v.y, v.z, v.w};
#pragma unroll
    for (int j = 0; j < 4; j++) {
        unsigned short hb = f2bf_rne(vv[j]);
        Whi[idx + j] = hb;
        Wlo[idx + j] = f2bf_rne(vv[j] - bf2f(hb));
    }
}

__global__ void prep_bias(const float* bih, const float* bhh, float* b01)
{
    int i = blockIdx.x*256 + threadIdx.x;
    if (i < 4096) b01[i] = bih[i] + bhh[i];
}

// ---------------------------------------------------------------------------
extern "C" void kernel_launch(void* const* d_in, const int* in_sizes, int n_in,
                              void* d_out, int out_size, void* d_ws, size_t ws_size,
                              hipStream_t stream)
{
    (void)in_sizes; (void)n_in; (void)out_size; (void)ws_size;
    const float* x_hist = (const float*)d_in[0];
    const float* W_in   = (const float*)d_in[1];
    const float* b_in   = (const float*)d_in[2];
    const float* W_ih   = (const float*)d_in[3];
    const float* W_hh   = (const float*)d_in[4];
    const float* b_ih   = (const float*)d_in[5];
    const float* b_hh   = (const float*)d_in[6];
    const float* W_out  = (const float*)d_in[7];
    const float* b_out  = (const float*)d_in[8];
    float* out = (float*)d_out;

    uint8_t* ws = (uint8_t*)d_ws;
    size_t off = 0;
    auto alloc = [&](size_t bytes) -> void* {
        void* p = ws + off; off += (bytes + 255) & ~(size_t)255; return p;
    };
    unsigned short* Whi = (unsigned short*)alloc((size_t)4*(1 << 20)*2);
    unsigned short* Wlo = (unsigned short*)alloc((size_t)4*(1 << 20)*2);
    float*          b01 = (float*)alloc(4096*4);
    uint8_t* state_base = ws + off;
    unsigned short* zhi  = (unsigned short*)alloc((size_t)2*SZ_HB*2);
    unsigned short* zlo  = (unsigned short*)alloc((size_t)2*SZ_HB*2);
    unsigned short* h0hi = (unsigned short*)alloc((size_t)2*SZ_HB*2);
    unsigned short* h0lo = (unsigned short*)alloc((size_t)2*SZ_HB*2);
    unsigned short* h1hi = (unsigned short*)alloc((size_t)2*SZ_HB*2);
    unsigned short* h1lo = (unsigned short*)alloc((size_t)2*SZ_HB*2);
    float* outbuf = (float*)alloc((size_t)512*64*4);
    unsigned* sync = (unsigned*)alloc(4096);
    size_t state_bytes = (size_t)((ws + off) - state_base);

    (void)hipFuncSetAttribute(reinterpret_cast<const void*>(persist),
                              hipFuncAttributeMaxDynamicSharedMemorySize, LDS_TOTAL);

    hipMemsetAsync(state_base, 0, state_bytes, stream);
    split_weights<<<4096, 256, 0, stream>>>(W_ih, W_hh, Whi, Wlo);
    prep_bias<<<16, 256, 0, stream>>>(b_ih, b_hh, b01);

    persist<<<256, 512, LDS_TOTAL, stream>>>(
        x_hist, W_in, b_in, Whi, Wlo, b01, W_out, b_out,
        zhi, zlo, h0hi, h0lo, h1hi, h1lo, outbuf, out, sync);
}